// Round 1
// baseline (1362.405 us; speedup 1.0000x reference)
//
#include <hip/hip_runtime.h>
#include <math.h>

// Problem constants
#define NTOK 131072
#define NEXP 64
#define KDIM 1024
#define NBINS 4096
#define CAP 8192
// 0-based ascending ranks for the column quantile (q=0.75, n=131072):
// idx = 0.75*(131071) = 98303.25 -> s[98303] + 0.25*(s[98304]-s[98303])
#define RLO 98303u
#define RHI 98304u

__device__ __forceinline__ int bin_of(float v) {
    int bn = (int)floorf((v + 8.0f) * 256.0f);   // 4096 bins over [-8, 8)
    bn = bn < 0 ? 0 : bn;
    bn = bn > (NBINS - 1) ? (NBINS - 1) : bn;
    return bn;
}

// ---------------- A0: transpose W [64,1024] -> WT [1024,64] ----------------
__global__ void transpose_w_kernel(const float* __restrict__ W, float* __restrict__ Wt) {
    int idx = blockIdx.x * 256 + threadIdx.x;   // 65536 elements
    int k = idx >> 6, e = idx & 63;
    Wt[k * 64 + e] = W[e * 1024 + k];
}

// ---------------- A: fp32 GEMM + bias + noise + histogram ----------------
// block: 256 thr; tile 64 tokens x 64 experts; K-tile 128; 4x4 microtile/thread
__global__ __launch_bounds__(256, 2)
void gemm_kernel(const float* __restrict__ x, const float* __restrict__ noise,
                 const float* __restrict__ Wt, const float* __restrict__ b,
                 float* __restrict__ logits, unsigned int* __restrict__ hist) {
    __shared__ float4 xs4[64 * 33];    // x tile, row stride 33 float4 = 132 floats (pad)
    __shared__ float4 wt4[128 * 16];   // WT tile [k][e/4], contiguous

    const int tid = threadIdx.x;
    const int tx = tid & 15;           // expert quad: e = 4*tx..4*tx+3
    const int ty = tid >> 4;           // token quad: t = 4*ty..4*ty+3  (ty 0..15)
    const long t0 = (long)blockIdx.x * 64;

    float4 acc[4];
    acc[0] = acc[1] = acc[2] = acc[3] = make_float4(0.f, 0.f, 0.f, 0.f);

    const int st_t  = tid >> 5;        // 0..7   (x staging)
    const int st_kk = tid & 31;        // float4 within row
    const int wk    = tid >> 4;        // 0..15  (WT staging)
    const int we4   = tid & 15;

    for (int kt = 0; kt < KDIM; kt += 128) {
        __syncthreads();
        #pragma unroll
        for (int c = 0; c < 8; ++c) {
            int tt = st_t + c * 8;
            xs4[tt * 33 + st_kk] =
                reinterpret_cast<const float4*>(x + (t0 + tt) * 1024 + kt)[st_kk];
        }
        #pragma unroll
        for (int c = 0; c < 8; ++c) {
            int kk = wk + c * 16;
            wt4[kk * 16 + we4] =
                reinterpret_cast<const float4*>(Wt + (long)(kt + kk) * 64)[we4];
        }
        __syncthreads();
        const float* xs = reinterpret_cast<const float*>(xs4);
        const int xbase = 4 * ty * 132;
        #pragma unroll 8
        for (int k = 0; k < 128; ++k) {
            float4 wv = wt4[k * 16 + tx];
            float x0 = xs[xbase + k];
            float x1 = xs[xbase + 132 + k];
            float x2 = xs[xbase + 264 + k];
            float x3 = xs[xbase + 396 + k];
            acc[0].x += x0 * wv.x; acc[0].y += x0 * wv.y; acc[0].z += x0 * wv.z; acc[0].w += x0 * wv.w;
            acc[1].x += x1 * wv.x; acc[1].y += x1 * wv.y; acc[1].z += x1 * wv.z; acc[1].w += x1 * wv.w;
            acc[2].x += x2 * wv.x; acc[2].y += x2 * wv.y; acc[2].z += x2 * wv.z; acc[2].w += x2 * wv.w;
            acc[3].x += x3 * wv.x; acc[3].y += x3 * wv.y; acc[3].z += x3 * wv.z; acc[3].w += x3 * wv.w;
        }
    }
    const float4 bb = reinterpret_cast<const float4*>(b)[tx];
    #pragma unroll
    for (int i = 0; i < 4; ++i) {
        long t = t0 + 4 * ty + i;
        float4 nz = reinterpret_cast<const float4*>(noise + t * 64)[tx];
        float4 r;
        r.x = acc[i].x + bb.x + 0.1f * nz.x;
        r.y = acc[i].y + bb.y + 0.1f * nz.y;
        r.z = acc[i].z + bb.z + 0.1f * nz.z;
        r.w = acc[i].w + bb.w + 0.1f * nz.w;
        reinterpret_cast<float4*>(logits + t * 64)[tx] = r;
        int e0 = 4 * tx;
        atomicAdd(&hist[(e0 + 0) * NBINS + bin_of(r.x)], 1u);
        atomicAdd(&hist[(e0 + 1) * NBINS + bin_of(r.y)], 1u);
        atomicAdd(&hist[(e0 + 2) * NBINS + bin_of(r.z)], 1u);
        atomicAdd(&hist[(e0 + 3) * NBINS + bin_of(r.w)], 1u);
    }
}

// ---------------- B1: find the bins holding ranks RLO/RHI per expert ----------------
__global__ void find_bins_kernel(const unsigned int* __restrict__ hist,
                                 int* __restrict__ blo, int* __restrict__ bhi,
                                 int* __restrict__ basearr) {
    __shared__ unsigned int psum[256];
    const int e = blockIdx.x, tid = threadIdx.x;
    const unsigned int* h = hist + e * NBINS;
    unsigned int loc[16];
    unsigned int s = 0;
    #pragma unroll
    for (int i = 0; i < 16; ++i) { loc[i] = h[tid * 16 + i]; s += loc[i]; }
    psum[tid] = s;
    __syncthreads();
    for (int off = 1; off < 256; off <<= 1) {       // inclusive scan
        unsigned int vv = (tid >= off) ? psum[tid - off] : 0u;
        __syncthreads();
        psum[tid] += vv;
        __syncthreads();
    }
    unsigned int cum = (tid == 0) ? 0u : psum[tid - 1];
    #pragma unroll
    for (int i = 0; i < 16; ++i) {
        unsigned int nb = cum + loc[i];
        // bin tid*16+i holds 0-based ranks [cum, nb)
        if (cum <= RLO && RLO < nb) { blo[e] = tid * 16 + i; basearr[e] = (int)cum; }
        if (cum <= RHI && RHI < nb) { bhi[e] = tid * 16 + i; }
        cum = nb;
    }
}

// ---------------- B2: extract candidate values in bins [blo..bhi] ----------------
__global__ void extract_kernel(const float* __restrict__ logits,
                               const int* __restrict__ blo, const int* __restrict__ bhi,
                               unsigned int* __restrict__ cnt, float* __restrict__ cand) {
    int i = blockIdx.x * 256 + threadIdx.x;     // 8388608 elements
    float v = logits[i];
    int e = i & 63;
    int bn = bin_of(v);
    if (bn >= blo[e] && bn <= bhi[e]) {
        unsigned int p = atomicAdd(&cnt[e], 1u);
        if (p < CAP) cand[e * CAP + p] = v;
    }
}

// ---------------- B3: sort candidates, compute exact column cut ----------------
__global__ void cuts_kernel(const float* __restrict__ cand, const unsigned int* __restrict__ cnt,
                            const int* __restrict__ basearr, float* __restrict__ cut) {
    __shared__ float s[CAP];
    const int e = blockIdx.x, tid = threadIdx.x;
    int n = (int)min(cnt[e], (unsigned int)CAP);
    int np2 = 2; while (np2 < n) np2 <<= 1;
    for (int i = tid; i < np2; i += 256) s[i] = (i < n) ? cand[e * CAP + i] : 3.0e38f;
    __syncthreads();
    for (int k = 2; k <= np2; k <<= 1) {
        for (int j = k >> 1; j > 0; j >>= 1) {
            for (int i = tid; i < np2; i += 256) {
                int ixj = i ^ j;
                if (ixj > i) {
                    float a = s[i], bb = s[ixj];
                    bool up = ((i & k) == 0);
                    if (up ? (a > bb) : (a < bb)) { s[i] = bb; s[ixj] = a; }
                }
            }
            __syncthreads();
        }
    }
    if (tid == 0) {
        int base = basearr[e];
        int r1 = (int)RLO - base, r2 = (int)RHI - base;
        r1 = max(0, min(r1, np2 - 1));
        r2 = max(0, min(r2, np2 - 1));
        float s1 = s[r1], s2 = s[r2];
        cut[e] = s1 + 0.25f * (s2 - s1);    // strictly inside (s1, s2) when s2 > s1
    }
}

// ---------------- C: per-row top-2 mask + softmax (wave per row) ----------------
__device__ __forceinline__ float wave_max_f(float v) {
    #pragma unroll
    for (int off = 32; off > 0; off >>= 1) v = fmaxf(v, __shfl_xor(v, off));
    return v;
}
__device__ __forceinline__ float wave_sum_f(float v) {
    #pragma unroll
    for (int off = 32; off > 0; off >>= 1) v += __shfl_xor(v, off);
    return v;
}
__device__ __forceinline__ double wave_max_d(double v) {
    #pragma unroll
    for (int off = 32; off > 0; off >>= 1) { double o = __shfl_xor(v, off); v = (o > v) ? o : v; }
    return v;
}
__device__ __forceinline__ double wave_sum_d(double v) {
    #pragma unroll
    for (int off = 32; off > 0; off >>= 1) v += __shfl_xor(v, off);
    return v;
}

__global__ __launch_bounds__(256)
void finalize_kernel(const float* __restrict__ logits, const float* __restrict__ cut,
                     const float* __restrict__ x, const float* __restrict__ W,
                     const float* __restrict__ noise, const float* __restrict__ b,
                     float* __restrict__ out) {
    const int tid = threadIdx.x;
    const int lane = tid & 63;                       // lane == expert
    const long row = (long)blockIdx.x * 4 + (tid >> 6);
    const float c = cut[lane];
    const float v = logits[row * 64 + lane];
    float m = (v > c) ? v : -100000.0f;

    // multiset top-3 (exclude one instance at a time, lowest lane first == np sort dup semantics)
    float v1 = wave_max_f(m);
    unsigned long long b1m = __ballot(m == v1);
    int l1 = __ffsll((unsigned long long)b1m) - 1;
    float mm = (lane == l1) ? -INFINITY : m;
    float v2 = wave_max_f(mm);
    unsigned long long b2m = __ballot(mm == v2);
    int l2 = __ffsll((unsigned long long)b2m) - 1;
    float mmm = (lane == l2) ? -INFINITY : mm;
    float v3 = wave_max_f(mmm);

    // row quantile: q=0.96875, n=64 -> idx 61.03125 -> s[61] + 0.03125*(s[62]-s[61])
    float qr = v3 + 0.03125f * (v2 - v3);
    bool kept = m > qr;
    int cntk = __popcll(__ballot(kept));
    bool risky = (cntk != 2) || (v2 - v3 < 1e-4f);   // wave-uniform

    if (!risky) {
        float ex = kept ? expf(m - v1) : 0.0f;
        float Z = wave_sum_f(ex);
        out[row * 64 + lane] = ex / Z;
        return;
    }
    // fp64 repair: recompute this row's logits exactly; rare (tens of rows)
    const float* xr = x + row * 1024;
    const float* wr = W + (long)lane * 1024;
    double a0 = 0.0, a1 = 0.0, a2 = 0.0, a3 = 0.0;
    for (int k = 0; k < 1024; k += 4) {
        a0 += (double)xr[k + 0] * (double)wr[k + 0];
        a1 += (double)xr[k + 1] * (double)wr[k + 1];
        a2 += (double)xr[k + 2] * (double)wr[k + 2];
        a3 += (double)xr[k + 3] * (double)wr[k + 3];
    }
    double lg = ((a0 + a1) + (a2 + a3)) + (double)b[lane] + 0.1 * (double)noise[row * 64 + lane];
    double md = (lg > (double)c) ? lg : -100000.0;
    double d1 = wave_max_d(md);
    unsigned long long db1 = __ballot(md == d1);
    int dl1 = __ffsll((unsigned long long)db1) - 1;
    double md2 = (lane == dl1) ? -(double)INFINITY : md;
    double d2 = wave_max_d(md2);
    unsigned long long db2 = __ballot(md2 == d2);
    int dl2 = __ffsll((unsigned long long)db2) - 1;
    double md3 = (lane == dl2) ? -(double)INFINITY : md2;
    double d3 = wave_max_d(md3);
    double qrd = d3 + 0.03125 * (d2 - d3);
    bool kd = md > qrd;
    int cd = __popcll(__ballot(kd));
    double od;
    if (cd == 0) od = 1.0 / 64.0;                    // fully masked row -> uniform softmax
    else {
        double exd = kd ? exp(md - d1) : 0.0;
        double Zd = wave_sum_d(exd);
        od = exd / Zd;
    }
    out[row * 64 + lane] = (float)od;
}

// ---------------- host ----------------
extern "C" void kernel_launch(void* const* d_in, const int* in_sizes, int n_in,
                              void* d_out, int out_size, void* d_ws, size_t ws_size,
                              hipStream_t stream) {
    const float* x     = (const float*)d_in[0];   // [131072,1024]
    const float* noise = (const float*)d_in[1];   // [131072,64]
    const float* W     = (const float*)d_in[2];   // [64,1024]
    const float* b     = (const float*)d_in[3];   // [64]
    float* out = (float*)d_out;                   // [131072,64]; doubles as logits scratch

    char* ws = (char*)d_ws;
    float*        Wt      = (float*)(ws + 0);             // 262144 B
    unsigned int* hist    = (unsigned int*)(ws + 262144); // 1048576 B
    unsigned int* cnt     = (unsigned int*)(ws + 1310720);// 256 B
    int*          blo     = (int*)(ws + 1310976);
    int*          bhi     = (int*)(ws + 1311232);
    int*          basearr = (int*)(ws + 1311488);
    float*        cut     = (float*)(ws + 1311744);
    float*        cand    = (float*)(ws + 1312000);       // 2097152 B; total ~3.3 MB

    hipMemsetAsync(hist, 0, 1048576 + 256, stream);       // hist + cnt contiguous

    hipLaunchKernelGGL(transpose_w_kernel, dim3(256), dim3(256), 0, stream, W, Wt);
    hipLaunchKernelGGL(gemm_kernel, dim3(NTOK / 64), dim3(256), 0, stream,
                       x, noise, Wt, b, out, hist);
    hipLaunchKernelGGL(find_bins_kernel, dim3(64), dim3(256), 0, stream,
                       hist, blo, bhi, basearr);
    hipLaunchKernelGGL(extract_kernel, dim3((NTOK * NEXP) / 256), dim3(256), 0, stream,
                       out, blo, bhi, cnt, cand);
    hipLaunchKernelGGL(cuts_kernel, dim3(64), dim3(256), 0, stream,
                       cand, cnt, basearr, cut);
    hipLaunchKernelGGL(finalize_kernel, dim3(NTOK / 4), dim3(256), 0, stream,
                       out, cut, x, W, noise, b, out);
}